// Round 4
// baseline (317.105 us; speedup 1.0000x reference)
//
#include <hip/hip_runtime.h>
#include <math.h>

// ---------- types ----------
typedef __attribute__((ext_vector_type(8)))  short  short8;   // 8 bf16 (4 VGPRs) MFMA A/B frag
typedef __attribute__((ext_vector_type(16))) float  f32x16;   // 32x32 MFMA C/D frag
typedef __attribute__((ext_vector_type(4)))  float  float4v;
typedef __attribute__((ext_vector_type(8)))  unsigned short ushort8;
typedef __attribute__((ext_vector_type(4)))  unsigned short ushort4v;

#define NDIM 4096
#define BM 256
#define BN 128
#define BK 64
#define T_TILES (NDIM / BK)              // 64
#define BUF_USH (BM * BK + BN * BK)      // 24576 ushorts = 48 KB per buffer

#define NA_BLOCKS 2048   // A-convert grid-stride blocks
#define NW_BLOCKS 4096   // W-transpose blocks (64x64 tiles over 4096^2)

// fp32 -> bf16, round-to-nearest-even
__device__ __forceinline__ unsigned short f2bf(float f) {
  unsigned u = __builtin_bit_cast(unsigned, f);
  u += 0x7fffu + ((u >> 16) & 1u);
  return (unsigned short)(u >> 16);
}

// async global->LDS DMA, 16B/lane. LDS dest must be wave-uniform base + lane*16.
__device__ __forceinline__ void gload_lds16(const unsigned short* g, unsigned short* l) {
  __builtin_amdgcn_global_load_lds(
      (const __attribute__((address_space(1))) void*)g,
      (__attribute__((address_space(3))) void*)l, 16, 0, 0);
}

// ---------- prep (unchanged: near-roofline streaming convert/transpose) ----------
__global__ __launch_bounds__(256)
void prep(const float* __restrict__ A, unsigned short* __restrict__ Abf,
          const float* __restrict__ W, unsigned short* __restrict__ Wt) {
  __shared__ unsigned short tile[64][72];   // [n_local][k_local], 9216 B
  const int t = threadIdx.x;                // 0..255
  if (blockIdx.x < NA_BLOCKS) {
    const int base   = blockIdx.x * 256 + t;
    const int stride = NA_BLOCKS * 256;
#pragma unroll
    for (int it = 0; it < 8; ++it) {
      const size_t idx = (size_t)(base + it * stride) * 4;   // float index
      float4v v = *(const float4v*)(A + idx);
      ushort4v o;
      o[0] = f2bf(v[0]); o[1] = f2bf(v[1]); o[2] = f2bf(v[2]); o[3] = f2bf(v[3]);
      *(ushort4v*)(Abf + idx) = o;
    }
  } else {
    const int b  = blockIdx.x - NA_BLOCKS;          // 0..4095
    const int n0 = (b & 63) * 64;
    const int k0 = (b >> 6) * 64;
    const int kq = t >> 4;                          // 0..15
    const int nc = (t & 15) * 4;
    float4v v[4];
#pragma unroll
    for (int r = 0; r < 4; ++r)
      v[r] = *(const float4v*)&W[(size_t)(k0 + kq * 4 + r) * NDIM + n0 + nc];
#pragma unroll
    for (int c = 0; c < 4; ++c) {                   // register transpose + convert
      ushort4v u;
#pragma unroll
      for (int r = 0; r < 4; ++r) u[r] = f2bf(v[r][c]);
      *(ushort4v*)&tile[nc + c][kq * 4] = u;
    }
    __syncthreads();
    const int n  = t >> 2;
    const int cb = (t & 3) * 16;
    unsigned short* dst = Wt + (size_t)(n0 + n) * NDIM + k0 + cb;
#pragma unroll
    for (int h = 0; h < 2; ++h) {
      ushort8 w8 = *(const ushort8*)&tile[n][cb + h * 8];
      *(ushort8*)(dst + h * 8) = w8;
    }
  }
}

// ---------- gemm: 256x128 tile, 8 WAVES, 3-buffer deep pipeline ----------
// R4: R3's counted-vmcnt pipeline was sound but ran 1 wave/SIMD (4-wave
// block, 1 block/CU) -> no co-resident wave to overlap MFMA with mem phases
// (m114 mechanism) -> MfmaUtil fell 41->36%. Fix: 8 waves (512 thr) per
// block, same 256x128 tile, wave grid 4Mx2N, per-wave tile 64x64. Each SIMD
// now holds 2 waves of the block: one issues MFMA while the other is in
// ds_read/stage -> overlap PLUS no vmcnt(0) drains.
// Pipeline (per iter): vmcnt(6) [tile t done, t+1's 6 loads stay in flight]
// -> raw s_barrier -> stage(t+2) -> 4x {6 ds_read_b128; setprio(1); 8 MFMA;
// setprio(0)}. One barrier/tile; vmcnt hits 0 only at the last tile.
// Safety: buffer staged at t was last read at t-1 (barrier-separated);
// ds_reads retire before each barrier (MFMA consumers force lgkm waits);
// all branches wave-uniform; every thread executes every barrier.
// Swizzle/fragment math identical to verified R0 kernel (XOR-8 chunks,
// C/D: col=lane&31, row=(reg&3)+8*(reg>>2)+4*(lane>>5)).
__global__ __launch_bounds__(512, 1)
void gemm_bt_quant(const unsigned short* __restrict__ A,
                   const unsigned short* __restrict__ Bt,
                   const float* __restrict__ bias,
                   float* __restrict__ C) {
  __shared__ unsigned short lds[3 * BUF_USH];   // 144 KB, 3 rotating buffers

  const int tid  = threadIdx.x;
  const int lane = tid & 63;
  const int wid  = tid >> 6;               // 8 waves: 4M x 2N
  const int wm   = (wid >> 1) * 64;        // 0,64,128,192
  const int wn   = (wid & 1) * 64;         // 0,64
  const int m0   = blockIdx.y * BM;
  const int n0   = blockIdx.x * BN;

  // staging: slot s = p*512+tid -> dest row s>>3, dest chunk s&7;
  // source logical chunk = (s&7) ^ (row&7). Rows advance 64/pass (mult of 8),
  // so row&7 == (tid>>3)&7 for all passes.
  const int srow = tid >> 3;                     // 0..63
  const int sc   = (tid & 7) ^ (srow & 7);       // swizzled source chunk
  const unsigned short* Ag = A  + (size_t)(m0 + srow) * NDIM + sc * 8;
  const unsigned short* Bg = Bt + (size_t)(n0 + srow) * NDIM + sc * 8;

  const int fr  = lane & 31;               // fragment row within 32-tile
  const int fh  = lane >> 5;               // K-half selector
  const int fsw = fr & 7;                  // read-side swizzle (row&7)

  f32x16 acc[2][2] = {};

  // stage tile k (K-offset k*BK) into buffer `buf`: 4 A-loads + 2 B-loads
  auto stage = [&](int k, int buf) {
    unsigned short* Asb = &lds[buf * BUF_USH];
    unsigned short* Bsb = Asb + BM * BK;
    const int ko = k * BK;
#pragma unroll
    for (int p = 0; p < 4; ++p)            // A rows p*64+srow (0..255)
      gload_lds16(Ag + ko + (size_t)(p * 64) * NDIM, &Asb[(p * 512 + tid) * 8]);
#pragma unroll
    for (int p = 0; p < 2; ++p)            // B rows p*64+srow (0..127)
      gload_lds16(Bg + ko + (size_t)(p * 64) * NDIM, &Bsb[(p * 512 + tid) * 8]);
  };

  // prologue: 2 tiles in flight
  stage(0, 0);
  stage(1, 1);

  int b = 0, b2 = 2;                       // b = t%3 (read buf), b2 = (t+2)%3 (stage buf)
  for (int t = 0; t < T_TILES; ++t) {
    // Wait for tile t's 6 loads; tile t+1's 6 stay in flight.
    if (t < T_TILES - 1)
      asm volatile("s_waitcnt vmcnt(6)" ::: "memory");
    else
      asm volatile("s_waitcnt vmcnt(0)" ::: "memory");
    __builtin_amdgcn_s_barrier();          // raw barrier: no compiler vmcnt(0) drain
    __builtin_amdgcn_sched_barrier(0);     // pin: nothing crosses the barrier

    if (t + 2 < T_TILES) stage(t + 2, b2); // target buffer last read at t-1: safe

    const unsigned short* Asb = &lds[b * BUF_USH];
    const unsigned short* Bsb = Asb + BM * BK;
#pragma unroll
    for (int h = 0; h < 4; ++h) {          // K16 steps within BK
      const int cph = (2 * h + fh) ^ fsw;  // physical chunk for this lane
      short8 af[2], bfr[2];
#pragma unroll
      for (int i = 0; i < 2; ++i)
        af[i] = *(const short8*)&Asb[(wm + i * 32 + fr) * BK + cph * 8];
#pragma unroll
      for (int j = 0; j < 2; ++j)
        bfr[j] = *(const short8*)&Bsb[(wn + j * 32 + fr) * BK + cph * 8];
      __builtin_amdgcn_s_setprio(1);       // T5: favor MFMA wave on the SIMD
#pragma unroll
      for (int i = 0; i < 2; ++i)
#pragma unroll
        for (int j = 0; j < 2; ++j)
          acc[i][j] = __builtin_amdgcn_mfma_f32_32x32x16_bf16(af[i], bfr[j], acc[i][j], 0, 0, 0);
      __builtin_amdgcn_s_setprio(0);
    }
    b  = (b  + 1 == 3) ? 0 : b  + 1;
    b2 = (b2 + 1 == 3) ? 0 : b2 + 1;
  }

  // epilogue: fused quant + bias (C/D: col=lane&31, row=(reg&3)+8*(reg>>2)+4*(lane>>5))
  const float inv = 1.0f / 256.0f;
#pragma unroll
  for (int j = 0; j < 2; ++j) {
    const int col = n0 + wn + j * 32 + fr;
    const float qb = rintf(bias[col] * 256.0f) * inv;
#pragma unroll
    for (int i = 0; i < 2; ++i) {
      const int rb = m0 + wm + i * 32 + 4 * fh;
#pragma unroll
      for (int r = 0; r < 16; ++r) {
        const int row = rb + (r & 3) + 8 * (r >> 2);
        C[(size_t)row * NDIM + col] = rintf(acc[i][j][r] * 256.0f) * inv + qb;
      }
    }
  }
}

// ---------- fallback (ws too small): fp32 tiled GEMM, exact ----------
__global__ void gemm_fb(const float* __restrict__ A, const float* __restrict__ W,
                        const float* __restrict__ bias, float* __restrict__ C) {
  __shared__ float As[32][33], Ws[32][33];
  int tx = threadIdx.x, ty = threadIdx.y;     // (32,8)
  int m0 = blockIdx.y * 32, n0 = blockIdx.x * 32;
  float acc[4] = {0.f, 0.f, 0.f, 0.f};
  for (int k0 = 0; k0 < NDIM; k0 += 32) {
#pragma unroll
    for (int i = 0; i < 4; ++i) {
      int r = ty + i * 8;
      As[r][tx] = A[(size_t)(m0 + r) * NDIM + k0 + tx];
      Ws[r][tx] = W[(size_t)(k0 + r) * NDIM + n0 + tx];
    }
    __syncthreads();
#pragma unroll
    for (int k = 0; k < 32; ++k) {
      float wv = Ws[k][tx];
#pragma unroll
      for (int i = 0; i < 4; ++i) acc[i] += As[ty + i * 8][k] * wv;
    }
    __syncthreads();
  }
  float qb = rintf(bias[n0 + tx] * 256.0f) * (1.0f / 256.0f);
#pragma unroll
  for (int i = 0; i < 4; ++i)
    C[(size_t)(m0 + ty + i * 8) * NDIM + n0 + tx] =
        rintf(acc[i] * 256.0f) * (1.0f / 256.0f) + qb;
}

extern "C" void kernel_launch(void* const* d_in, const int* in_sizes, int n_in,
                              void* d_out, int out_size, void* d_ws, size_t ws_size,
                              hipStream_t stream) {
  const float* A    = (const float*)d_in[0];
  const float* W    = (const float*)d_in[1];
  const float* bias = (const float*)d_in[2];
  float* C = (float*)d_out;
  const size_t nElem = (size_t)NDIM * NDIM;

  if (ws_size >= nElem * 4) {   // need 2 bf16 matrices = 64 MB
    unsigned short* Abf = (unsigned short*)d_ws;
    unsigned short* Wt  = Abf + nElem;
    prep<<<NA_BLOCKS + NW_BLOCKS, 256, 0, stream>>>(A, Abf, W, Wt);
    gemm_bt_quant<<<dim3(NDIM / BN, NDIM / BM), 512, 0, stream>>>(Abf, Wt, bias, C);
  } else {
    gemm_fb<<<dim3(128, 128), dim3(32, 8), 0, stream>>>(A, W, bias, C);
  }
}

// Round 5
// 298.373 us; speedup vs baseline: 1.0628x; 1.0628x over previous
//
#include <hip/hip_runtime.h>
#include <math.h>

// ---------- types ----------
typedef __attribute__((ext_vector_type(8)))  short  short8;   // 8 bf16 (4 VGPRs) MFMA A/B frag
typedef __attribute__((ext_vector_type(16))) float  f32x16;   // 32x32 MFMA C/D frag
typedef __attribute__((ext_vector_type(4)))  float  float4v;
typedef __attribute__((ext_vector_type(8)))  unsigned short ushort8;
typedef __attribute__((ext_vector_type(4)))  unsigned short ushort4v;

#define NDIM 4096
#define BM 256
#define BN 256
#define BK 64
#define T_TILES (NDIM / BK)              // 64
#define HALF_USH 8192                    // one half-tile: 128 rows x 64 k x 2B = 16 KB
#define B_BASE   (5 * HALF_USH)          // B-ring starts after 5 A-slots

#define NA_BLOCKS 2048   // A-convert grid-stride blocks
#define NW_BLOCKS 4096   // W-transpose blocks (64x64 tiles over 4096^2)

// fp32 -> bf16, round-to-nearest-even
__device__ __forceinline__ unsigned short f2bf(float f) {
  unsigned u = __builtin_bit_cast(unsigned, f);
  u += 0x7fffu + ((u >> 16) & 1u);
  return (unsigned short)(u >> 16);
}

// async global->LDS DMA, 16B/lane. LDS dest must be wave-uniform base + lane*16.
__device__ __forceinline__ void gload_lds16(const unsigned short* g, unsigned short* l) {
  __builtin_amdgcn_global_load_lds(
      (const __attribute__((address_space(1))) void*)g,
      (__attribute__((address_space(3))) void*)l, 16, 0, 0);
}

// ---------- prep (unchanged: near-roofline streaming convert/transpose) ----------
__global__ __launch_bounds__(256)
void prep(const float* __restrict__ A, unsigned short* __restrict__ Abf,
          const float* __restrict__ W, unsigned short* __restrict__ Wt) {
  __shared__ unsigned short tile[64][72];   // [n_local][k_local], 9216 B
  const int t = threadIdx.x;                // 0..255
  if (blockIdx.x < NA_BLOCKS) {
    const int base   = blockIdx.x * 256 + t;
    const int stride = NA_BLOCKS * 256;
#pragma unroll
    for (int it = 0; it < 8; ++it) {
      const size_t idx = (size_t)(base + it * stride) * 4;   // float index
      float4v v = *(const float4v*)(A + idx);
      ushort4v o;
      o[0] = f2bf(v[0]); o[1] = f2bf(v[1]); o[2] = f2bf(v[2]); o[3] = f2bf(v[3]);
      *(ushort4v*)(Abf + idx) = o;
    }
  } else {
    const int b  = blockIdx.x - NA_BLOCKS;          // 0..4095
    const int n0 = (b & 63) * 64;
    const int k0 = (b >> 6) * 64;
    const int kq = t >> 4;                          // 0..15
    const int nc = (t & 15) * 4;
    float4v v[4];
#pragma unroll
    for (int r = 0; r < 4; ++r)
      v[r] = *(const float4v*)&W[(size_t)(k0 + kq * 4 + r) * NDIM + n0 + nc];
#pragma unroll
    for (int c = 0; c < 4; ++c) {                   // register transpose + convert
      ushort4v u;
#pragma unroll
      for (int r = 0; r < 4; ++r) u[r] = f2bf(v[r][c]);
      *(ushort4v*)&tile[nc + c][kq * 4] = u;
    }
    __syncthreads();
    const int n  = t >> 2;
    const int cb = (t & 3) * 16;
    unsigned short* dst = Wt + (size_t)(n0 + n) * NDIM + k0 + cb;
#pragma unroll
    for (int h = 0; h < 2; ++h) {
      ushort8 w8 = *(const ushort8*)&tile[n][cb + h * 8];
      *(ushort8*)(dst + h * 8) = w8;
    }
  }
}

// ---------- gemm: 256x256 tile, 8 waves, 4-phase/K-tile interleaved pipeline ----------
// R5: T3+T4 proper port (m196/m201 lesson: counted vmcnt pays ONLY inside a
// fine per-phase ds_read||gload||MFMA interleave; R3/R4's coarse split = -12%).
// Geometry: 8 waves (2M x 4N), per-wave 128x64 output (4x2 of 32x32), BK=64.
// LDS = half-tile (128rows x 64k = 16KB) rings: A-ring 5 slots + B-ring 4
// slots = 144KB. Per K-tile t, 4 phases; phase p computes m-tile p (8 MFMA).
// Staging (1 half / phase): p0:A0(t+1)  p1:A1(t+1)  p2:B0(t+2)  p3:B1(t+2).
// Ring-safety proof (phase numbers global, 4 per tile):
//  - A-half a=2u+i staged at 4(u-1)+i, slot a%5 overwritten by a+5 at phase
//    4u+4+i >= last read 4u+3 + 1  -> safe (barrier-separated).
//  - B-half b=2u+i staged at 4(u-2)+2+i, slot b%4 overwritten by b+4 at
//    phase 4u+2+i > last read 4u (bk preload, lgkm-retired in phase 4u).
//  - availability: vmcnt(4) at each tile's p0 leaves exactly B0,B1(t+1)
//    (4 loads, not yet needed) outstanding; everything tile t needs is
//    older -> landed. Last tile uses vmcnt(0) (its prefetches were the
//    youngest issues). vmcnt never 0 before that; 1 vmcnt per K-tile.
//  - reads of phase p are lgkm-retired before phase p's MFMA (dataflow),
//    hence before the next barrier; all barriers wave-uniform.
// Fragment math / XOR-8 swizzle identical to harness-verified R0 kernel
// (chunk c of row r stored at c^(r&7); r&7 invariant under half offsets).
__global__ __launch_bounds__(512, 2)
void gemm_bt_quant(const unsigned short* __restrict__ A,
                   const unsigned short* __restrict__ Bt,
                   const float* __restrict__ bias,
                   float* __restrict__ C) {
  __shared__ unsigned short lds[9 * HALF_USH];   // 147456 B

  const int tid  = threadIdx.x;            // 0..511
  const int lane = tid & 63;
  const int wid  = tid >> 6;               // 8 waves
  const int wr   = wid >> 2;               // 0..1  (M)
  const int wc   = wid & 3;                // 0..3  (N)
  const int hb   = wc >> 1;                // which B-half this wave reads
  const int bnr  = (wc & 1) * 64;          // row base within B-half

  // XCD-bijective swizzle: 256 blocks, 8 XCDs, 32 consecutive tiles per XCD
  const int bid  = blockIdx.y * 16 + blockIdx.x;
  const int swz  = (bid & 7) * 32 + (bid >> 3);
  const int m0   = (swz >> 4) * BM;
  const int n0   = (swz & 15) * BN;

  // staging source (per-thread): slot s=p2*512+tid -> half-row s>>3, chunk s&7;
  // source chunk = (s&7)^(row&7); row advances by 64/pass -> row&7=(tid>>3)&7.
  const int srow = tid >> 3;                     // 0..63
  const int sc   = (tid & 7) ^ (srow & 7);
  const unsigned short* Ag = A  + (size_t)(m0 + srow) * NDIM + sc * 8;
  const unsigned short* Bg = Bt + (size_t)(n0 + srow) * NDIM + sc * 8;

  const int fr  = lane & 31;               // fragment row within 32-tile
  const int fh  = lane >> 5;               // K-half selector
  const int fsw = fr & 7;                  // read-side swizzle

  auto stageA = [&](int tt, int ha, int slot) {
    unsigned short* dst = &lds[slot * HALF_USH];
    const unsigned short* g = Ag + (size_t)(ha * 128) * NDIM + tt * 64;
    gload_lds16(g,                       &dst[tid * 8]);
    gload_lds16(g + (size_t)64 * NDIM,   &dst[(512 + tid) * 8]);
  };
  auto stageB = [&](int tt, int hb2, int slot) {
    unsigned short* dst = &lds[B_BASE + slot * HALF_USH];
    const unsigned short* g = Bg + (size_t)(hb2 * 128) * NDIM + tt * 64;
    gload_lds16(g,                       &dst[tid * 8]);
    gload_lds16(g + (size_t)64 * NDIM,   &dst[(512 + tid) * 8]);
  };

  f32x16 acc[4][2] = {};

  // prologue: B(0), A(0), B(1) -> 12 loads; vmcnt(4) at t=0 covers B(0)+A(0)
  stageB(0, 0, 0);
  stageB(0, 1, 1);
  stageA(0, 0, 0);
  stageA(0, 1, 1);
  stageB(1, 0, 2);
  stageB(1, 1, 3);

  int raA = wr;          // slot of A-half(wr) of tile t   : (2t+wr)%5
  int rbB = hb;          // slot of B-half(hb) of tile t   : (2t+hb)&3
  int sA0 = 2, sA1 = 3;  // stage slots for A0/A1(t+1)     : (2t+2)%5,(2t+3)%5
  int sB0 = 0, sB1 = 1;  // stage slots for B0/B1(t+2)     : (2t+4)&3,(2t+5)&3

  for (int t = 0; t < T_TILES; ++t) {
    const unsigned short* Ah = &lds[raA * HALF_USH];
    const unsigned short* Bh = &lds[B_BASE + rbB * HALF_USH];
    short8 bk[2][4];
#pragma unroll
    for (int p = 0; p < 4; ++p) {
      if (p == 0) {
        if (t < T_TILES - 1) asm volatile("s_waitcnt vmcnt(4)" ::: "memory");
        else                 asm volatile("s_waitcnt vmcnt(0)" ::: "memory");
      }
      __builtin_amdgcn_s_barrier();
      __builtin_amdgcn_sched_barrier(0);

      if (p == 0) {                        // bk preload: both n-tiles, 4 k16-steps
#pragma unroll
        for (int j = 0; j < 2; ++j)
#pragma unroll
          for (int h = 0; h < 4; ++h)
            bk[j][h] = *(const short8*)&Bh[(bnr + j * 32 + fr) * 64 + ((2 * h + fh) ^ fsw) * 8];
      }
      short8 af[4];                        // m-tile p, 4 k16-steps
#pragma unroll
      for (int h = 0; h < 4; ++h)
        af[h] = *(const short8*)&Ah[(p * 32 + fr) * 64 + ((2 * h + fh) ^ fsw) * 8];

      if (p == 0 && t + 1 < T_TILES) stageA(t + 1, 0, sA0);
      if (p == 1 && t + 1 < T_TILES) stageA(t + 1, 1, sA1);
      if (p == 2 && t + 2 < T_TILES) stageB(t + 2, 0, sB0);
      if (p == 3 && t + 2 < T_TILES) stageB(t + 2, 1, sB1);

      asm volatile("s_waitcnt lgkmcnt(0)" ::: "memory");
      __builtin_amdgcn_sched_barrier(0);
      __builtin_amdgcn_s_setprio(1);
#pragma unroll
      for (int h = 0; h < 4; ++h)
#pragma unroll
        for (int j = 0; j < 2; ++j)
          acc[p][j] = __builtin_amdgcn_mfma_f32_32x32x16_bf16(af[h], bk[j][h], acc[p][j], 0, 0, 0);
      __builtin_amdgcn_s_setprio(0);
    }
    raA += 2; if (raA >= 5) raA -= 5;
    sA0 += 2; if (sA0 >= 5) sA0 -= 5;
    sA1 += 2; if (sA1 >= 5) sA1 -= 5;
    rbB = (rbB + 2) & 3;
    sB0 = (sB0 + 2) & 3;
    sB1 = (sB1 + 2) & 3;
  }

  // epilogue: fused quant + bias (C/D: col=lane&31, row=(reg&3)+8*(reg>>2)+4*(lane>>5))
  const float inv = 1.0f / 256.0f;
#pragma unroll
  for (int j = 0; j < 2; ++j) {
    const int col = n0 + wc * 64 + j * 32 + fr;
    const float qb = rintf(bias[col] * 256.0f) * inv;
#pragma unroll
    for (int p = 0; p < 4; ++p) {
      const int rb = m0 + wr * 128 + p * 32 + 4 * fh;
#pragma unroll
      for (int r = 0; r < 16; ++r) {
        const int row = rb + (r & 3) + 8 * (r >> 2);
        C[(size_t)row * NDIM + col] = rintf(acc[p][j][r] * 256.0f) * inv + qb;
      }
    }
  }
}

// ---------- fallback (ws too small): fp32 tiled GEMM, exact ----------
__global__ void gemm_fb(const float* __restrict__ A, const float* __restrict__ W,
                        const float* __restrict__ bias, float* __restrict__ C) {
  __shared__ float As[32][33], Ws[32][33];
  int tx = threadIdx.x, ty = threadIdx.y;     // (32,8)
  int m0 = blockIdx.y * 32, n0 = blockIdx.x * 32;
  float acc[4] = {0.f, 0.f, 0.f, 0.f};
  for (int k0 = 0; k0 < NDIM; k0 += 32) {
#pragma unroll
    for (int i = 0; i < 4; ++i) {
      int r = ty + i * 8;
      As[r][tx] = A[(size_t)(m0 + r) * NDIM + k0 + tx];
      Ws[r][tx] = W[(size_t)(k0 + r) * NDIM + n0 + tx];
    }
    __syncthreads();
#pragma unroll
    for (int k = 0; k < 32; ++k) {
      float wv = Ws[k][tx];
#pragma unroll
      for (int i = 0; i < 4; ++i) acc[i] += As[ty + i * 8][k] * wv;
    }
    __syncthreads();
  }
  float qb = rintf(bias[n0 + tx] * 256.0f) * (1.0f / 256.0f);
#pragma unroll
  for (int i = 0; i < 4; ++i)
    C[(size_t)(m0 + ty + i * 8) * NDIM + n0 + tx] =
        rintf(acc[i] * 256.0f) * (1.0f / 256.0f) + qb;
}

extern "C" void kernel_launch(void* const* d_in, const int* in_sizes, int n_in,
                              void* d_out, int out_size, void* d_ws, size_t ws_size,
                              hipStream_t stream) {
  const float* A    = (const float*)d_in[0];
  const float* W    = (const float*)d_in[1];
  const float* bias = (const float*)d_in[2];
  float* C = (float*)d_out;
  const size_t nElem = (size_t)NDIM * NDIM;

  if (ws_size >= nElem * 4) {   // need 2 bf16 matrices = 64 MB
    unsigned short* Abf = (unsigned short*)d_ws;
    unsigned short* Wt  = Abf + nElem;
    prep<<<NA_BLOCKS + NW_BLOCKS, 256, 0, stream>>>(A, Abf, W, Wt);
    gemm_bt_quant<<<dim3(16, 16), 512, 0, stream>>>(Abf, Wt, bias, C);
  } else {
    gemm_fb<<<dim3(128, 128), dim3(32, 8), 0, stream>>>(A, W, bias, C);
  }
}

// Round 6
// 295.930 us; speedup vs baseline: 1.0716x; 1.0083x over previous
//
#include <hip/hip_runtime.h>
#include <math.h>

// ---------- types ----------
typedef __attribute__((ext_vector_type(8)))  short  short8;   // 8 bf16 (4 VGPRs) MFMA A/B frag
typedef __attribute__((ext_vector_type(16))) float  f32x16;   // 32x32 MFMA C/D frag
typedef __attribute__((ext_vector_type(4)))  float  float4v;
typedef __attribute__((ext_vector_type(8)))  unsigned short ushort8;
typedef __attribute__((ext_vector_type(4)))  unsigned short ushort4v;

#define NDIM 4096
#define BM 256
#define BN 256
#define BK 64
#define T_TILES (NDIM / BK)   // 64
#define IMG_USH 8192          // one half-tile image: 1024 chunks x 16B = 16 KB

// fp32 -> bf16, round-to-nearest-even
__device__ __forceinline__ unsigned short f2bf(float f) {
  unsigned u = __builtin_bit_cast(unsigned, f);
  u += 0x7fffu + ((u >> 16) & 1u);
  return (unsigned short)(u >> 16);
}

// async global->LDS DMA, 16B/lane. LDS dest must be wave-uniform base + lane*16.
__device__ __forceinline__ void gload_lds16(const unsigned short* g, unsigned short* l) {
  __builtin_amdgcn_global_load_lds(
      (const __attribute__((address_space(1))) void*)g,
      (__attribute__((address_space(3))) void*)l, 16, 0, 0);
}

// ---------- prep: emit A and W^T as FRAGMENT-MAJOR images ----------
// Image (per 128-row half x 64-k tile) = 1024 16B-chunks; chunk index
// s = (p*4+h)*64 + fh*32 + fr  <->  rows p*32+fr (p=0..3, fr=0..31),
// k-bytes h*32 + fh*16 (h=0..3, fh=0..1). GEMM then stages with src =
// base + tid*16 (linear DMA) and reads frags at base + lane*16
// (contiguous per wave -> ZERO bank conflicts, no address VALU).
// A-part (blocks 0..2047): image (mb,kt). Thread t owns chunk t of each
//   p-quarter: 2 float4 loads (64B/row-pair coalesced via fh-halves),
//   1 ushort8 store, stores wave-contiguous.
// W-part (blocks 2048..4095): image (nb,kt). Thread owns 4n x 8k block:
//   8 coalesced float4 row-loads, register transpose, 4 chunk stores
//   (64B contiguous per thread, 2KB per 32 lanes). No LDS anywhere.
__global__ __launch_bounds__(256)
void prep(const float* __restrict__ A, unsigned short* __restrict__ Abf,
          const float* __restrict__ W, unsigned short* __restrict__ Wt) {
  const int t = threadIdx.x;
  if (blockIdx.x < 2048) {
    const int b  = blockIdx.x;
    const int mb = b >> 6, kt = b & 63;
    const int h  = (t >> 6) & 3, fh = (t >> 5) & 1, fr = t & 31;
    const float* src0 = A + (size_t)(mb * 128 + fr) * NDIM + kt * 64 + h * 16 + fh * 8;
    unsigned short* dst = Abf + ((size_t)(mb * 64 + kt) * 1024 + t) * 8;
#pragma unroll
    for (int p = 0; p < 4; ++p) {            // chunk p*256 + t
      const float* s = src0 + (size_t)(p * 32) * NDIM;
      float4v a = *(const float4v*)s;
      float4v c = *(const float4v*)(s + 4);
      ushort8 o;
      o[0] = f2bf(a[0]); o[1] = f2bf(a[1]); o[2] = f2bf(a[2]); o[3] = f2bf(a[3]);
      o[4] = f2bf(c[0]); o[5] = f2bf(c[1]); o[6] = f2bf(c[2]); o[7] = f2bf(c[3]);
      *(ushort8*)(dst + (size_t)p * 2048) = o;
    }
  } else {
    const int b  = blockIdx.x - 2048;
    const int nb = b >> 6, kt = b & 63;
    const int n0 = (t & 31) * 4;             // local n quad base (0..124)
    const int kq = t >> 5;                   // k octet 0..7
    float4v v[8];
#pragma unroll
    for (int r = 0; r < 8; ++r)              // 512B contiguous per (kq,r) row
      v[r] = *(const float4v*)&W[(size_t)(kt * 64 + kq * 8 + r) * NDIM + nb * 128 + n0];
    const int q  = (t & 31) >> 3;            // n-subtile 0..3
    const int h  = kq >> 1, fh = kq & 1;
    unsigned short* img = Wt + (size_t)(nb * 64 + kt) * IMG_USH;
#pragma unroll
    for (int c = 0; c < 4; ++c) {            // register transpose -> full chunks
      const int fr = (n0 + c) & 31;
      ushort8 o;
#pragma unroll
      for (int r = 0; r < 8; ++r) o[r] = f2bf(v[r][c]);
      *(ushort8*)(img + ((size_t)((q * 4 + h) * 64 + fh * 32 + fr)) * 8) = o;
    }
  }
}

// ---------- gemm: 256x256, 8 waves, two-barrier phases, fragment-major LDS ----------
// R6 restructure (m201-faithful): per tile u, 4 phases; each phase =
//   { ds_reads (af[4]; +bk[2][4] at p0) ; stage one half ; [vmcnt @p3] ;
//     s_barrier ; lgkmcnt(0) ; setprio(1) ; 8 MFMA ; setprio(0) ; s_barrier }
// Reads issue BEFORE barrier1 -> they execute while the wave's previous MFMA
// queue drains (the overlap R5 lacked). All LDS reads/DMA are base+lane*16:
// conflict-free by construction (fragment-major images).
// Staging plan: p0:A0(u+1) p1:A1(u+1) p2:B0(u+2) p3:B1(u+2); ring depth 2
// per (matrix,half) -> 8 x 16KB = 128 KB.
// Wait-schedule proof (loads = 2 per half):
//  - gate at (u,p3) pre-barrier1: vmcnt(4). Outstanding there (steady) =
//    B(u+1)[4, from (u-1)] + A(u+1)[4] + B(u+2)[4] = 12 -> wait to 4 leaves
//    exactly B(u+2) in flight; confirms A(u+1),B(u+1) = everything tile u+1
//    reads. Gate precedes barrier1 -> after the barrier ALL waves' loads for
//    tile u+1 are confirmed (each wave gated its own). Tail: u>=T-2 -> vmcnt(0).
//  - write-after-read: stage at (u,pX) targets slot (u+?)&1 != slot u&1 for A;
//    B(u+2) shares slot u&1 with B(u) but B(u)'s only reads (p0) are lgkm-
//    drained before (u,p0)'s MFMA, >=2 barriers before the (u,p2) DMA issue.
//    Cross-wave: DMA issue follows barrier2 crossings that require all waves'
//    prior lgkm drains. All control flow wave-uniform.
// Fragment semantics identical to harness-verified R0/R5 (same values, new
// addresses); C/D: col=lane&31, row=(reg&3)+8*(reg>>2)+4*(lane>>5).
__global__ __launch_bounds__(512, 1)
void gemm_bt_quant(const unsigned short* __restrict__ Abf,
                   const unsigned short* __restrict__ Wt,
                   const float* __restrict__ bias,
                   float* __restrict__ C) {
  __shared__ unsigned short lds[8 * IMG_USH];   // A00,A01,A10,A11,B00,B01,B10,B11

  const int tid  = threadIdx.x;            // 0..511
  const int lane = tid & 63;
  const int wid  = tid >> 6;               // 8 waves: 2M x 4N
  const int wr   = wid >> 2;               // 0..1
  const int wc   = wid & 3;                // 0..3
  const int hb   = wc >> 1;                // B-half this wave reads

  // XCD-bijective swizzle (256 blocks % 8 == 0)
  const int bid  = blockIdx.y * 16 + blockIdx.x;
  const int swz  = (bid & 7) * 32 + (bid >> 3);
  const int m0   = (swz >> 4) * BM;
  const int n0   = (swz & 15) * BN;
  const int mb0  = (swz >> 4) * 2;
  const int nb0  = (swz & 15) * 2;

  const unsigned short* Aimg = Abf + (size_t)mb0 * 64 * IMG_USH;
  const unsigned short* Bimg = Wt  + (size_t)nb0 * 64 * IMG_USH;

  auto stageA = [&](int u, int ha) {
    unsigned short* dst = &lds[(ha * 2 + (u & 1)) * IMG_USH];
    const unsigned short* src = Aimg + ((size_t)(ha * 64 + u)) * IMG_USH + tid * 8;
    gload_lds16(src,        dst + tid * 8);
    gload_lds16(src + 4096, dst + 4096 + tid * 8);
  };
  auto stageB = [&](int u, int h2) {
    unsigned short* dst = &lds[(4 + h2 * 2 + (u & 1)) * IMG_USH];
    const unsigned short* src = Bimg + ((size_t)(h2 * 64 + u)) * IMG_USH + tid * 8;
    gload_lds16(src,        dst + tid * 8);
    gload_lds16(src + 4096, dst + 4096 + tid * 8);
  };

  f32x16 acc[4][2] = {};

  // prologue: B(0), A(0), B(1); confirm A(0),B(0), keep B(1) in flight
  stageB(0, 0); stageB(0, 1);
  stageA(0, 0); stageA(0, 1);
  stageB(1, 0); stageB(1, 1);
  asm volatile("s_waitcnt vmcnt(4)" ::: "memory");
  __builtin_amdgcn_s_barrier();

  const int lofs = lane * 8;               // per-lane chunk offset (ushorts)

  for (int u = 0; u < T_TILES; ++u) {
    const unsigned short* Ah = &lds[(wr * 2 + (u & 1)) * IMG_USH];
    const unsigned short* Bh = &lds[(4 + hb * 2 + (u & 1)) * IMG_USH + (wc & 1) * 4096];
    short8 bk[2][4];
#pragma unroll
    for (int p = 0; p < 4; ++p) {
      // ---- pre-barrier: register loads + DMA issue (overlaps prev MFMA drain)
      if (p == 0) {
#pragma unroll
        for (int j = 0; j < 2; ++j)
#pragma unroll
          for (int h = 0; h < 4; ++h)
            bk[j][h] = *(const short8*)&Bh[j * 2048 + h * 512 + lofs];
      }
      short8 af[4];
#pragma unroll
      for (int h = 0; h < 4; ++h)
        af[h] = *(const short8*)&Ah[p * 2048 + h * 512 + lofs];

      if (p == 0 && u + 1 < T_TILES) stageA(u + 1, 0);
      if (p == 1 && u + 1 < T_TILES) stageA(u + 1, 1);
      if (p == 2 && u + 2 < T_TILES) stageB(u + 2, 0);
      if (p == 3 && u + 2 < T_TILES) stageB(u + 2, 1);

      __builtin_amdgcn_sched_barrier(0);
      if (p == 3) {
        if (u < T_TILES - 2) asm volatile("s_waitcnt vmcnt(4)" ::: "memory");
        else                 asm volatile("s_waitcnt vmcnt(0)" ::: "memory");
      }
      __builtin_amdgcn_s_barrier();
      asm volatile("s_waitcnt lgkmcnt(0)" ::: "memory");
      __builtin_amdgcn_sched_barrier(0);       // rule #18: no MFMA hoist
      __builtin_amdgcn_s_setprio(1);
#pragma unroll
      for (int h = 0; h < 4; ++h)
#pragma unroll
        for (int j = 0; j < 2; ++j)
          acc[p][j] = __builtin_amdgcn_mfma_f32_32x32x16_bf16(af[h], bk[j][h], acc[p][j], 0, 0, 0);
      __builtin_amdgcn_s_setprio(0);
      __builtin_amdgcn_s_barrier();
      __builtin_amdgcn_sched_barrier(0);
    }
  }

  // epilogue: fused quant + bias
  const int fr = lane & 31;
  const int fh = lane >> 5;
  const float inv = 1.0f / 256.0f;
#pragma unroll
  for (int j = 0; j < 2; ++j) {
    const int col = n0 + wc * 64 + j * 32 + fr;
    const float qb = rintf(bias[col] * 256.0f) * inv;
#pragma unroll
    for (int p = 0; p < 4; ++p) {
      const int rb = m0 + wr * 128 + p * 32 + 4 * fh;
#pragma unroll
      for (int r = 0; r < 16; ++r) {
        const int row = rb + (r & 3) + 8 * (r >> 2);
        C[(size_t)row * NDIM + col] = rintf(acc[p][j][r] * 256.0f) * inv + qb;
      }
    }
  }
}

// ---------- fallback (ws too small): fp32 tiled GEMM, exact ----------
__global__ void gemm_fb(const float* __restrict__ A, const float* __restrict__ W,
                        const float* __restrict__ bias, float* __restrict__ C) {
  __shared__ float As[32][33], Ws[32][33];
  int tx = threadIdx.x, ty = threadIdx.y;     // (32,8)
  int m0 = blockIdx.y * 32, n0 = blockIdx.x * 32;
  float acc[4] = {0.f, 0.f, 0.f, 0.f};
  for (int k0 = 0; k0 < NDIM; k0 += 32) {
#pragma unroll
    for (int i = 0; i < 4; ++i) {
      int r = ty + i * 8;
      As[r][tx] = A[(size_t)(m0 + r) * NDIM + k0 + tx];
      Ws[r][tx] = W[(size_t)(k0 + r) * NDIM + n0 + tx];
    }
    __syncthreads();
#pragma unroll
    for (int k = 0; k < 32; ++k) {
      float wv = Ws[k][tx];
#pragma unroll
      for (int i = 0; i < 4; ++i) acc[i] += As[ty + i * 8][k] * wv;
    }
    __syncthreads();
  }
  float qb = rintf(bias[n0 + tx] * 256.0f) * (1.0f / 256.0f);
#pragma unroll
  for (int i = 0; i < 4; ++i)
    C[(size_t)(m0 + ty + i * 8) * NDIM + n0 + tx] =
        rintf(acc[i] * 256.0f) * (1.0f / 256.0f) + qb;
}

extern "C" void kernel_launch(void* const* d_in, const int* in_sizes, int n_in,
                              void* d_out, int out_size, void* d_ws, size_t ws_size,
                              hipStream_t stream) {
  const float* A    = (const float*)d_in[0];
  const float* W    = (const float*)d_in[1];
  const float* bias = (const float*)d_in[2];
  float* C = (float*)d_out;
  const size_t nElem = (size_t)NDIM * NDIM;

  if (ws_size >= nElem * 4) {   // need 2 bf16 matrices = 64 MB
    unsigned short* Abf = (unsigned short*)d_ws;
    unsigned short* Wt  = Abf + nElem;
    prep<<<4096, 256, 0, stream>>>(A, Abf, W, Wt);
    gemm_bt_quant<<<dim3(16, 16), 512, 0, stream>>>(Abf, Wt, bias, C);
  } else {
    gemm_fb<<<dim3(128, 128), dim3(32, 8), 0, stream>>>(A, W, bias, C);
  }
}